// Round 10
// baseline (162.972 us; speedup 1.0000x reference)
//
#include <hip/hip_runtime.h>
#include <math.h>

#define E_ 256
#define W_ 20
#define S_ 5
#define Q_ 300
#define D_ 512
#define ALPHA_ 37.0f
#define QPAD 304
#define NT 19            // ceil(304/16) q-tiles of 16

typedef __attribute__((ext_vector_type(8))) short bf16x8;
typedef __attribute__((ext_vector_type(4))) float f32x4;
typedef __attribute__((ext_vector_type(2))) unsigned int u32x2;
typedef __attribute__((ext_vector_type(4))) unsigned int u32x4;

__device__ __forceinline__ unsigned short f2bf(float x) {
    unsigned int u = __builtin_bit_cast(unsigned int, x);
    u += 0x7fffu + ((u >> 16) & 1u);          // RNE
    return (unsigned short)(u >> 16);
}
__device__ __forceinline__ float bf2f(unsigned short h) {
    unsigned int u = ((unsigned int)h) << 16;
    return __builtin_bit_cast(float, u);
}

// LDS fragment read from s_ss: row-major [row][512 bf16], row stride 1024B,
// 16B chunks XOR-swizzled by (row&7). k0 = bf16 index, multiple of 8.
__device__ __forceinline__ bf16x8 ldfrag(const char* base, int row, int k0) {
    const int phys = (k0 >> 3) ^ (row & 7);
    return *reinterpret_cast<const bf16x8*>(base + row * 1024 + phys * 16);
}

// Load one 16-row Q tile fragment set from GLOBAL into registers (transient).
// Fragment layout (r5/r7/r8-verified): row = tile*16+ln15, k-chunk = k*32+hi*8.
__device__ __forceinline__ float qtile_load(const float* __restrict__ xqe,
                                            int tile, int ln15, int hi,
                                            bf16x8* qf) {
    const int q  = tile * 16 + ln15;
    const int qc = (q < Q_) ? q : (Q_ - 1);           // clamp tail rows
    const float* qrow = xqe + (size_t)qc * D_;
    float q2 = 0.f;
    #pragma unroll
    for (int k = 0; k < 16; ++k) {
        const int d0 = k * 32 + hi * 8;
        const float4 a = *reinterpret_cast<const float4*>(qrow + d0);
        const float4 b = *reinterpret_cast<const float4*>(qrow + d0 + 4);
        q2 += a.x * a.x + a.y * a.y + a.z * a.z + a.w * a.w
            + b.x * b.x + b.y * b.y + b.z * b.z + b.w * b.w;
        bf16x8 v;
        v[0] = (short)f2bf(a.x); v[1] = (short)f2bf(a.y);
        v[2] = (short)f2bf(a.z); v[3] = (short)f2bf(a.w);
        v[4] = (short)f2bf(b.x); v[5] = (short)f2bf(b.y);
        v[6] = (short)f2bf(b.z); v[7] = (short)f2bf(b.w);
        qf[k] = v;
    }
    // full ||q||^2 in every lane after folding the 4 hi-quarters
    q2 += __shfl_xor(q2, 16);
    q2 += __shfl_xor(q2, 32);
    return q2;
}

__global__ __launch_bounds__(1024, 4) void fused10(const float* __restrict__ xs,
                                                   const float* __restrict__ xq,
                                                   const float* __restrict__ temp_p,
                                                   float* __restrict__ out) {
    // 59 KB static LDS
    __shared__ __align__(16) char  s_ss[32 * 1024];   // shot_sum bf16 swz -> proto_n bf16
    __shared__ __align__(16) float s_buf[W_ * QPAD];  // -dist -> weights
    __shared__ float s_q2[320];                       // ||q||^2
    __shared__ float s_m2[32];                        // ||mean||^2
    __shared__ float s_minv[32];                      // 1/||proto||
    __shared__ float s_red[8 * W_];                   // norm partials

    const int e    = blockIdx.x;
    const int tid  = threadIdx.x;                     // 0..1023
    const int lane = tid & 63;
    const int wv   = tid >> 6;                        // wave 0..15
    const int ln15 = lane & 15;
    const int hi   = lane >> 4;

    const float* xse = xs + (size_t)e * (W_ * S_ * D_);
    const float* xqe = xq + (size_t)e * (Q_ * D_);
    const float  temp = *temp_p;

    // ---- P0: zero pad rows 20..31 of s_ss ----
    if (tid < 12 * 64) {
        const int row = 20 + (tid >> 6), ch = tid & 63;
        u32x4 z = {0u, 0u, 0u, 0u};
        *reinterpret_cast<u32x4*>(s_ss + row * 1024 + ch * 16) = z;
    }
    // ---- P1: shot_sum -> s_ss bf16, float4-vectorized ----
    #pragma unroll
    for (int it = 0; it < 3; ++it) {
        const int idx = it * 1024 + tid;
        if (idx < W_ * 128) {
            const int w  = idx >> 7;
            const int dq = idx & 127;
            const float4* p0 = reinterpret_cast<const float4*>(xse + (w * S_) * D_ + dq * 4);
            float4 a = p0[0];
            #pragma unroll
            for (int s = 1; s < S_; ++s) {
                const float4 t = p0[s * (D_ / 4)];
                a.x += t.x; a.y += t.y; a.z += t.z; a.w += t.w;
            }
            u32x2 v;
            v[0] = (unsigned int)f2bf(a.x) | ((unsigned int)f2bf(a.y) << 16);
            v[1] = (unsigned int)f2bf(a.z) | ((unsigned int)f2bf(a.w) << 16);
            *reinterpret_cast<u32x2*>(s_ss + w * 1024 + (((dq >> 1) ^ (w & 7)) << 4) +
                                      (dq & 1) * 8) = v;
        }
    }
    __syncthreads();

    // ---- P3 pass 0 loads issued EARLY (hide HBM latency under P2) ----
    bf16x8 qf[16];
    float q2r = qtile_load(xqe, wv, ln15, hi, qf);
    {
        const int q = wv * 16 + ln15;
        if (hi == 0) s_q2[q] = q2r;                   // q <= 255 here
    }

    // ---- P2: m2[w] = ||shot_mean||^2 from bf16 shot_sum ----
    for (int w = wv; w < W_; w += 16) {
        bf16x8 v = *reinterpret_cast<const bf16x8*>(s_ss + w * 1024 + ((lane ^ (w & 7)) << 4));
        float p = 0.f;
        #pragma unroll
        for (int j = 0; j < 8; ++j) { float f = bf2f((unsigned short)v[j]); p += f * f; }
        #pragma unroll
        for (int off = 32; off; off >>= 1) p += __shfl_xor(p, off);
        if (lane == 0) s_m2[w] = p * (1.f / (S_ * S_));
    }
    __syncthreads();

    // ---- P3: dist MFMA; wave wv does tile wv, waves 0-2 also tiles 16-18 ----
    #pragma unroll
    for (int pass = 0; pass < 2; ++pass) {
        const int tile = pass ? (16 + wv) : wv;
        if (pass && tile >= NT) break;
        if (pass) {
            q2r = qtile_load(xqe, tile, ln15, hi, qf);
            const int q = tile * 16 + ln15;
            if (hi == 0) s_q2[q] = q2r;               // q <= 303 < 320
        }
        f32x4 acc0 = {0.f, 0.f, 0.f, 0.f};
        f32x4 acc1 = {0.f, 0.f, 0.f, 0.f};
        #pragma unroll
        for (int k = 0; k < 16; ++k) {
            const bf16x8 a0 = ldfrag(s_ss, ln15,      k * 32 + hi * 8);
            const bf16x8 a1 = ldfrag(s_ss, 16 + ln15, k * 32 + hi * 8);
            acc0 = __builtin_amdgcn_mfma_f32_16x16x32_bf16(a0, qf[k], acc0, 0, 0, 0);
            acc1 = __builtin_amdgcn_mfma_f32_16x16x32_bf16(a1, qf[k], acc1, 0, 0, 0);
        }
        // C/D (HW-verified r3): col(N=q)=ln15, row(M=w)=hi*4+r
        const int q = tile * 16 + ln15;
        if (q < Q_) {
            #pragma unroll
            for (int r = 0; r < 4; ++r) {
                const int w0 = hi * 4 + r;
                float d2 = s_m2[w0] + q2r - 0.4f * acc0[r];
                s_buf[w0 * QPAD + q] = -sqrtf(fmaxf(d2, 0.f));
                const int w1 = 16 + hi * 4 + r;
                if (w1 < W_) {
                    float e2 = s_m2[w1] + q2r - 0.4f * acc1[r];
                    s_buf[w1 * QPAD + q] = -sqrtf(fmaxf(e2, 0.f));
                }
            }
        }
    }
    __syncthreads();

    // ---- P4: softmax over q per w ----
    for (int w = wv; w < W_; w += 16) {
        float mx = -1e30f;
        for (int q = lane; q < Q_; q += 64) mx = fmaxf(mx, s_buf[w * QPAD + q]);
        #pragma unroll
        for (int off = 32; off; off >>= 1) mx = fmaxf(mx, __shfl_xor(mx, off));
        float sm = 0.f;
        for (int q = lane; q < Q_; q += 64) {
            float ex = __expf(s_buf[w * QPAD + q] - mx);
            s_buf[w * QPAD + q] = ex;
            sm += ex;
        }
        #pragma unroll
        for (int off = 32; off; off >>= 1) sm += __shfl_xor(sm, off);
        const float inv = 1.f / sm;
        for (int q = lane; q < Q_; q += 64) s_buf[w * QPAD + q] *= inv;
    }
    __syncthreads();

    // ---- P5: pooled + proto + norms + proto_n (waves 0-7; barriers flattened) ----
    {
        float pr[W_];
        if (tid < 512) {
            #pragma unroll
            for (int w = 0; w < W_; ++w) pr[w] = 0.f;
            for (int q0 = 0; q0 < Q_; q0 += 4) {
                const float qv0 = xqe[(q0 + 0) * D_ + tid];
                const float qv1 = xqe[(q0 + 1) * D_ + tid];
                const float qv2 = xqe[(q0 + 2) * D_ + tid];
                const float qv3 = xqe[(q0 + 3) * D_ + tid];
                #pragma unroll
                for (int w = 0; w < W_; ++w) {
                    const float4 wt = *reinterpret_cast<const float4*>(&s_buf[w * QPAD + q0]);
                    pr[w] += wt.x * qv0 + wt.y * qv1 + wt.z * qv2 + wt.w * qv3;
                }
            }
            const int chb = tid >> 3;
            #pragma unroll
            for (int w = 0; w < W_; ++w) {
                unsigned short h =
                    *(unsigned short*)(s_ss + w * 1024 + ((chb ^ (w & 7)) << 4) + (tid & 7) * 2);
                pr[w] = (bf2f(h) + ALPHA_ * pr[w]) * (1.f / (S_ + ALPHA_));
            }
            #pragma unroll
            for (int w = 0; w < W_; ++w) {
                float p = pr[w] * pr[w];
                #pragma unroll
                for (int off = 32; off; off >>= 1) p += __shfl_xor(p, off);
                if (lane == 0) s_red[wv * W_ + w] = p;
            }
        }
        __syncthreads();
        if (tid < W_) {
            float p = 0.f;
            #pragma unroll
            for (int k = 0; k < 8; ++k) p += s_red[k * W_ + tid];
            s_minv[tid] = 1.f / fmaxf(sqrtf(p), 1e-12f);
        }
        __syncthreads();
        if (tid < 512) {
            const int chb = tid >> 3;
            #pragma unroll
            for (int w = 0; w < W_; ++w) {
                *(unsigned short*)(s_ss + w * 1024 + ((chb ^ (w & 7)) << 4) + (tid & 7) * 2) =
                    f2bf(pr[w] * s_minv[w]);
            }
        }
        // ---- hoisted P6 pass-0 load: global+regs only, hides under barrier ----
        (void)qtile_load(xqe, wv, ln15, hi, qf);
        __syncthreads();
    }

    // ---- P6: logits MFMA; direct store ----
    const size_t eoff = (size_t)e * (Q_ * W_);
    #pragma unroll
    for (int pass = 0; pass < 2; ++pass) {
        const int tile = pass ? (16 + wv) : wv;
        if (pass && tile >= NT) break;
        if (pass) (void)qtile_load(xqe, tile, ln15, hi, qf);
        f32x4 acc0 = {0.f, 0.f, 0.f, 0.f};
        f32x4 acc1 = {0.f, 0.f, 0.f, 0.f};
        #pragma unroll
        for (int k = 0; k < 16; ++k) {
            const bf16x8 b0 = ldfrag(s_ss, ln15,      k * 32 + hi * 8);
            const bf16x8 b1 = ldfrag(s_ss, 16 + ln15, k * 32 + hi * 8);
            acc0 = __builtin_amdgcn_mfma_f32_16x16x32_bf16(qf[k], b0, acc0, 0, 0, 0);
            acc1 = __builtin_amdgcn_mfma_f32_16x16x32_bf16(qf[k], b1, acc1, 0, 0, 0);
        }
        // C/D: row(M=q)=hi*4+r, col(N=w)=ln15
        #pragma unroll
        for (int r = 0; r < 4; ++r) {
            const int q = tile * 16 + hi * 4 + r;
            if (q < Q_) {
                const float scale = temp / fmaxf(sqrtf(s_q2[q]), 1e-12f);
                out[eoff + q * W_ + ln15] = scale * acc0[r];      // w = ln15 < 16
                const int w1 = 16 + ln15;
                if (w1 < W_) out[eoff + q * W_ + w1] = scale * acc1[r];
            }
        }
    }
}

extern "C" void kernel_launch(void* const* d_in, const int* in_sizes, int n_in,
                              void* d_out, int out_size, void* d_ws, size_t ws_size,
                              hipStream_t stream) {
    const float* xs = (const float*)d_in[0];
    const float* xq = (const float*)d_in[1];
    const float* tp = (const float*)d_in[2];
    fused10<<<E_, 1024, 0, stream>>>(xs, xq, tp, (float*)d_out);
}